// Round 3
// baseline (92.159 us; speedup 1.0000x reference)
//
#include <hip/hip_runtime.h>
#include <hip/hip_bf16.h>
#include <math.h>

// Problem constants (SEFusion): x [N=25, C=256, H=48, W=176] f32
// CHW = 256*48*176 = 2,162,688 floats = 540,672 float4 per token.
#define CHW      2162688
#define V4       540672          // CHW / 4
#define BPT      64              // reduction blocks per token
#define V4_BLK   8448            // V4 / BPT
#define ITERS    33              // V4_BLK / 256
#define MAXCAV   5

// ---------------- Kernel 1: per-token sum + max (deterministic tree) -------
__global__ __launch_bounds__(256) void k_reduce(const float4* __restrict__ x,
                                                float* __restrict__ psum,
                                                float* __restrict__ pmax) {
    const int t   = blockIdx.y;      // token
    const int blk = blockIdx.x;      // 0..BPT-1
    const long base = (long)t * V4 + (long)blk * V4_BLK;

    float s = 0.0f;
    float mx = -INFINITY;
    #pragma unroll 4
    for (int i = 0; i < ITERS; ++i) {
        float4 v = x[base + i * 256 + threadIdx.x];
        s += (v.x + v.y) + (v.z + v.w);
        mx = fmaxf(mx, fmaxf(fmaxf(v.x, v.y), fmaxf(v.z, v.w)));
    }

    __shared__ float ssum[256];
    __shared__ float smax[256];
    ssum[threadIdx.x] = s;
    smax[threadIdx.x] = mx;
    __syncthreads();
    #pragma unroll
    for (int off = 128; off > 0; off >>= 1) {
        if (threadIdx.x < off) {
            ssum[threadIdx.x] += ssum[threadIdx.x + off];
            smax[threadIdx.x] = fmaxf(smax[threadIdx.x], smax[threadIdx.x + off]);
        }
        __syncthreads();
    }
    if (threadIdx.x == 0) {
        psum[t * BPT + blk] = ssum[0];
        pmax[t * BPT + blk] = smax[0];
    }
}

// ---------------- Kernel 2: fused gate + weighted sum + bias + relu --------
template <int LEN>
__device__ __forceinline__ void apply_body(const float4* __restrict__ x,
                                           const float* __restrict__ c,
                                           float bias, int start,
                                           long obase, int idx,
                                           float4* __restrict__ out) {
    float4 acc = make_float4(bias, bias, bias, bias);
    #pragma unroll
    for (int m = 0; m < LEN; ++m) {
        float4 v = x[(long)(start + m) * V4 + idx];
        acc.x += c[m] * v.x;
        acc.y += c[m] * v.y;
        acc.z += c[m] * v.z;
        acc.w += c[m] * v.w;
    }
    acc.x = fmaxf(acc.x, 0.0f);
    acc.y = fmaxf(acc.y, 0.0f);
    acc.z = fmaxf(acc.z, 0.0f);
    acc.w = fmaxf(acc.w, 0.0f);
    out[obase + idx] = acc;
}

__global__ __launch_bounds__(256) void k_apply(const float4* __restrict__ x,
                                               const int*   __restrict__ record_len,
                                               const float* __restrict__ psum,
                                               const float* __restrict__ pmax,
                                               const float* __restrict__ W1,
                                               const float* __restrict__ W2,
                                               const float* __restrict__ conv_w,
                                               const float* __restrict__ conv_b,
                                               float4* __restrict__ out,
                                               int ntok) {
    const int b = blockIdx.y;

    // ---- per-block gate prologue (redundant; partials are L2-resident) ----
    __shared__ float tsum[32];
    __shared__ float tmax[32];
    __shared__ float scoef[MAXCAV];
    __shared__ int   sstart;
    const int wave = threadIdx.x >> 6;
    const int lane = threadIdx.x & 63;

    for (int t = wave; t < ntok; t += 4) {
        float s = psum[t * BPT + lane];
        float m = pmax[t * BPT + lane];
        #pragma unroll
        for (int off = 32; off > 0; off >>= 1) {
            s += __shfl_xor(s, off, 64);
            m = fmaxf(m, __shfl_xor(m, off, 64));
        }
        if (lane == 0) { tsum[t] = s; tmax[t] = m; }
    }
    __syncthreads();

    if (threadIdx.x == 0) {
        int start = 0;
        for (int i = 0; i < b; ++i) start += record_len[i];
        const int len = record_len[b];
        sstart = start;

        float xsq[2 * MAXCAV];
        #pragma unroll
        for (int m = 0; m < MAXCAV; ++m) {
            const bool valid = m < len;
            xsq[m]          = valid ? tsum[start + m] * (1.0f / (float)CHW) : 0.0f;
            xsq[MAXCAV + m] = valid ? tmax[start + m] : 0.0f;   // zero-pad slot: max = 0
        }
        float h[MAXCAV];
        #pragma unroll
        for (int j = 0; j < MAXCAV; ++j) {
            float a = 0.0f;
            #pragma unroll
            for (int k = 0; k < 2 * MAXCAV; ++k) a += xsq[k] * W1[j * 2 * MAXCAV + k];
            h[j] = 1.0f / (1.0f + expf(-a));
        }
        #pragma unroll
        for (int m = 0; m < MAXCAV; ++m) {
            float g = 0.0f;
            #pragma unroll
            for (int j = 0; j < MAXCAV; ++j) g += h[j] * W2[m * MAXCAV + j];
            scoef[m] = conv_w[m] * fmaxf(g, 0.0f);
        }
    }
    __syncthreads();

    // ---- main apply loop: 8 float4 per thread ----
    const int len   = record_len[b];
    const int start = sstart;
    float c[MAXCAV];
    #pragma unroll
    for (int m = 0; m < MAXCAV; ++m) c[m] = scoef[m];
    const float bias  = conv_b[0];
    const long  obase = (long)b * V4;

    int idx = blockIdx.x * 2048 + threadIdx.x;   // 8 float4 per thread
    #pragma unroll
    for (int r = 0; r < 8; ++r, idx += 256) {
        switch (len) {
            case 1: apply_body<1>(x, c, bias, start, obase, idx, out); break;
            case 2: apply_body<2>(x, c, bias, start, obase, idx, out); break;
            case 3: apply_body<3>(x, c, bias, start, obase, idx, out); break;
            case 4: apply_body<4>(x, c, bias, start, obase, idx, out); break;
            default: apply_body<5>(x, c, bias, start, obase, idx, out); break;
        }
    }
}

extern "C" void kernel_launch(void* const* d_in, const int* in_sizes, int n_in,
                              void* d_out, int out_size, void* d_ws, size_t ws_size,
                              hipStream_t stream) {
    const float* x  = (const float*)d_in[0];
    const int*   rl = (const int*)d_in[1];
    const float* W1 = (const float*)d_in[2];
    const float* W2 = (const float*)d_in[3];
    const float* cw = (const float*)d_in[4];
    const float* cb = (const float*)d_in[5];
    float4* out = (float4*)d_out;

    char* ws = (char*)d_ws;
    float* psum = (float*)(ws);             // 25*64 floats = 6400 B
    float* pmax = (float*)(ws + 6400);      // 6400 B

    const int ntok = in_sizes[0] / CHW;     // 25
    const int bs   = in_sizes[1];           // 8

    k_reduce<<<dim3(BPT, ntok), 256, 0, stream>>>((const float4*)x, psum, pmax);
    k_apply<<<dim3(V4 / 2048, bs), 256, 0, stream>>>((const float4*)x, rl, psum, pmax,
                                                     W1, W2, cw, cb, out, ntok);
}

// Round 4
// 84.658 us; speedup vs baseline: 1.0886x; 1.0886x over previous
//
#include <hip/hip_runtime.h>
#include <hip/hip_bf16.h>
#include <math.h>

// Problem constants (SEFusion): x [N=25, C=256, H=48, W=176] f32
// CHW = 256*48*176 = 2,162,688 floats = 540,672 float4 per token.
#define CHW      2162688
#define V4       540672          // CHW / 4
#define BPT      64              // reduction blocks per token
#define V4_BLK   8448            // V4 / BPT
#define ITERS    33              // V4_BLK / 256
#define MAXCAV   5

typedef float f32x4 __attribute__((ext_vector_type(4)));

// ---------------- Kernel 1: per-token sum + max (deterministic tree) -------
__global__ __launch_bounds__(256) void k_reduce(const float4* __restrict__ x,
                                                float* __restrict__ psum,
                                                float* __restrict__ pmax) {
    const int t   = blockIdx.y;      // token
    const int blk = blockIdx.x;      // 0..BPT-1
    const long base = (long)t * V4 + (long)blk * V4_BLK;

    float s = 0.0f;
    float mx = -INFINITY;
    #pragma unroll 4
    for (int i = 0; i < ITERS; ++i) {
        float4 v = x[base + i * 256 + threadIdx.x];
        s += (v.x + v.y) + (v.z + v.w);
        mx = fmaxf(mx, fmaxf(fmaxf(v.x, v.y), fmaxf(v.z, v.w)));
    }

    __shared__ float ssum[256];
    __shared__ float smax[256];
    ssum[threadIdx.x] = s;
    smax[threadIdx.x] = mx;
    __syncthreads();
    #pragma unroll
    for (int off = 128; off > 0; off >>= 1) {
        if (threadIdx.x < off) {
            ssum[threadIdx.x] += ssum[threadIdx.x + off];
            smax[threadIdx.x] = fmaxf(smax[threadIdx.x], smax[threadIdx.x + off]);
        }
        __syncthreads();
    }
    if (threadIdx.x == 0) {
        psum[t * BPT + blk] = ssum[0];
        pmax[t * BPT + blk] = smax[0];
    }
}

// ---------------- Kernel 2: finish reduction + gate MLP + coefficients -----
__global__ __launch_bounds__(256) void k_gate(const float* __restrict__ psum,
                                              const float* __restrict__ pmax,
                                              const int*   __restrict__ record_len,
                                              const float* __restrict__ W1,
                                              const float* __restrict__ W2,
                                              const float* __restrict__ conv_w,
                                              int*   __restrict__ starts,
                                              float* __restrict__ coefs,
                                              int bs, int ntok) {
    __shared__ float tsum[32];
    __shared__ float tmax[32];
    const int wave = threadIdx.x >> 6;
    const int lane = threadIdx.x & 63;

    for (int t = wave; t < ntok; t += 4) {
        float s = psum[t * BPT + lane];
        float m = pmax[t * BPT + lane];
        #pragma unroll
        for (int off = 32; off > 0; off >>= 1) {
            s += __shfl_xor(s, off, 64);
            m = fmaxf(m, __shfl_xor(m, off, 64));
        }
        if (lane == 0) { tsum[t] = s; tmax[t] = m; }
    }
    __syncthreads();

    if ((int)threadIdx.x < bs) {
        const int b = threadIdx.x;
        int start = 0;
        for (int i = 0; i < b; ++i) start += record_len[i];
        const int len = record_len[b];

        float xsq[2 * MAXCAV];
        #pragma unroll
        for (int m = 0; m < MAXCAV; ++m) {
            const bool valid = m < len;
            xsq[m]          = valid ? tsum[start + m] * (1.0f / (float)CHW) : 0.0f;
            xsq[MAXCAV + m] = valid ? tmax[start + m] : 0.0f;   // zero-pad slot: max = 0
        }
        float h[MAXCAV];
        #pragma unroll
        for (int j = 0; j < MAXCAV; ++j) {
            float a = 0.0f;
            #pragma unroll
            for (int k = 0; k < 2 * MAXCAV; ++k) a += xsq[k] * W1[j * 2 * MAXCAV + k];
            h[j] = 1.0f / (1.0f + expf(-a));
        }
        starts[b] = start;
        #pragma unroll
        for (int m = 0; m < MAXCAV; ++m) {
            float g = 0.0f;
            #pragma unroll
            for (int j = 0; j < MAXCAV; ++j) g += h[j] * W2[m * MAXCAV + j];
            g = fmaxf(g, 0.0f);                 // relu
            coefs[b * MAXCAV + m] = conv_w[m] * g;
        }
    }
}

// ---------------- Kernel 3: balanced weighted sum + bias + relu ------------
// Each block handles the SAME 512-float4 window for ALL batches: per-block
// bytes = 25 reads + 8 writes of 8 KB -> perfectly uniform cost, no tail.
template <int LEN>
__device__ __forceinline__ void apply_one(const float4* __restrict__ x,
                                          const float* __restrict__ c,
                                          float bias, int start,
                                          long obase, int idx,
                                          float4* __restrict__ out) {
    float ax = bias, ay = bias, az = bias, aw = bias;
    #pragma unroll
    for (int m = 0; m < LEN; ++m) {
        float4 v = x[(long)(start + m) * V4 + idx];
        ax += c[m] * v.x;
        ay += c[m] * v.y;
        az += c[m] * v.z;
        aw += c[m] * v.w;
    }
    f32x4 acc;
    acc.x = fmaxf(ax, 0.0f);
    acc.y = fmaxf(ay, 0.0f);
    acc.z = fmaxf(az, 0.0f);
    acc.w = fmaxf(aw, 0.0f);
    __builtin_nontemporal_store(acc, (f32x4*)(out + obase + idx));
}

template <int LEN>
__device__ __forceinline__ void apply_pair(const float4* __restrict__ x,
                                           const float* __restrict__ c,
                                           float bias, int start,
                                           long obase, int idx0,
                                           float4* __restrict__ out) {
    apply_one<LEN>(x, c, bias, start, obase, idx0, out);
    apply_one<LEN>(x, c, bias, start, obase, idx0 + 256, out);
}

__global__ __launch_bounds__(256) void k_apply(const float4* __restrict__ x,
                                               const int*   __restrict__ record_len,
                                               const int*   __restrict__ starts,
                                               const float* __restrict__ coefs,
                                               const float* __restrict__ conv_b,
                                               float4* __restrict__ out,
                                               int bs) {
    const int idx0 = blockIdx.x * 512 + threadIdx.x;   // 2 float4/thread/batch
    const float bias = conv_b[0];

    for (int b = 0; b < bs; ++b) {
        const int len   = record_len[b];
        const int start = starts[b];
        float c[MAXCAV];
        #pragma unroll
        for (int m = 0; m < MAXCAV; ++m) c[m] = coefs[b * MAXCAV + m];
        const long obase = (long)b * V4;

        switch (len) {
            case 1:  apply_pair<1>(x, c, bias, start, obase, idx0, out); break;
            case 2:  apply_pair<2>(x, c, bias, start, obase, idx0, out); break;
            case 3:  apply_pair<3>(x, c, bias, start, obase, idx0, out); break;
            case 4:  apply_pair<4>(x, c, bias, start, obase, idx0, out); break;
            default: apply_pair<5>(x, c, bias, start, obase, idx0, out); break;
        }
    }
}

extern "C" void kernel_launch(void* const* d_in, const int* in_sizes, int n_in,
                              void* d_out, int out_size, void* d_ws, size_t ws_size,
                              hipStream_t stream) {
    const float* x  = (const float*)d_in[0];
    const int*   rl = (const int*)d_in[1];
    const float* W1 = (const float*)d_in[2];
    const float* W2 = (const float*)d_in[3];
    const float* cw = (const float*)d_in[4];
    const float* cb = (const float*)d_in[5];
    float4* out = (float4*)d_out;

    char* ws = (char*)d_ws;
    float* psum   = (float*)(ws);             // 25*64 floats = 6400 B
    float* pmax   = (float*)(ws + 6400);      // 6400 B
    int*   starts = (int*)  (ws + 12800);     // 32 B
    float* coefs  = (float*)(ws + 12832);     // 160 B

    const int ntok = in_sizes[0] / CHW;       // 25
    const int bs   = in_sizes[1];             // 8

    k_reduce<<<dim3(BPT, ntok), 256, 0, stream>>>((const float4*)x, psum, pmax);
    k_gate<<<1, 256, 0, stream>>>(psum, pmax, rl, W1, W2, cw, starts, coefs, bs, ntok);
    k_apply<<<V4 / 512, 256, 0, stream>>>((const float4*)x, rl, starts, coefs, cb, out, bs);
}